// Round 12
// baseline (64.662 us; speedup 1.0000x reference)
//
#include <hip/hip_runtime.h>

#define D 16
#define OUTD 153                 // 1 + 16 + 16 + 120
#define TILE_ROWS 16
#define THREADS 128

typedef float f32x4 __attribute__((ext_vector_type(4)));

// R11 (NT stores, 63.4us) + occupancy/phase-diversity lever: 128-thread blocks,
// 16-row tiles -> 9.56 KiB LDS, 16 blocks/CU (vs 8), 2-wave barrier scope (vs 4).
// Same emit ranges (8 x ~19 cols), now 4 ranges per wave (2x serialization --
// ~77 issue slots, still hidden under the ~350cy/tile store drain budget).

template<int LO, int HI>
__device__ __forceinline__ void emit_cols(const float xv[D], float* dst) {
    if (LO <= 0 && 0 < HI) dst[0] = 1.0f;
#pragma unroll
    for (int k = 0; k < D; ++k) {
        const int c1 = 1 + k;                    // x / 16^0.25
        if (c1 >= LO && c1 < HI) dst[c1] = xv[k] * 0.5f;
        const int c2 = 17 + k;                   // x^2 / (4*sqrt(2))
        if (c2 >= LO && c2 < HI) dst[c2] = xv[k] * xv[k] * 0.17677669529663687f;
    }
#pragma unroll
    for (int i = 0; i < D; ++i) {
#pragma unroll
        for (int j = i + 1; j < D; ++j) {        // x_i*x_j / 4
            const int c = 33 + (15 * i - (i * (i - 1)) / 2) + (j - i - 1);
            if (c >= LO && c < HI) dst[c] = xv[i] * xv[j] * 0.25f;
        }
    }
}

__global__ __launch_bounds__(THREADS) void taylor_fm_kernel(const float* __restrict__ x,
                                                            float* __restrict__ out,
                                                            int nrows) {
    __shared__ float olds[TILE_ROWS * OUTD];     // 9792 B -> 16 blocks/CU (32 waves)
    const int tid = threadIdx.x;
    const int r   = tid & 15;                    // row within tile (8 threads per row)
    const int r8  = tid >> 4;                    // col-range id 0..7
    const int r0  = blockIdx.x * TILE_ROWS;
    const int row = r0 + r;

    if (row < nrows) {
        const float4* xrow = reinterpret_cast<const float4*>(x + (size_t)row * D);
        float xv[D];
#pragma unroll
        for (int m = 0; m < 4; ++m) {
            float4 v = xrow[m];
            xv[4 * m + 0] = v.x; xv[4 * m + 1] = v.y;
            xv[4 * m + 2] = v.z; xv[4 * m + 3] = v.w;
        }
        float* dst = olds + r * OUTD;            // banks (25r+c)%32: conflict-free
        switch (r8) {
            case 0: emit_cols<0,   20 >(xv, dst); break;
            case 1: emit_cols<20,  39 >(xv, dst); break;
            case 2: emit_cols<39,  58 >(xv, dst); break;
            case 3: emit_cols<58,  77 >(xv, dst); break;
            case 4: emit_cols<77,  96 >(xv, dst); break;
            case 5: emit_cols<96,  115>(xv, dst); break;
            case 6: emit_cols<115, 134>(xv, dst); break;
            case 7: emit_cols<134, 153>(xv, dst); break;
        }
    }
    __syncthreads();

    // Flat, fully coalesced float4 NONTEMPORAL stores.
    // Chunk = 16*153*4 = 9792 B (16B-aligned), nelem = 2448 (mult of 4 -> nf4 = 612).
    const int nrow_blk = min(TILE_ROWS, nrows - r0);
    const int nelem = nrow_blk * OUTD;
    const int nf4 = nelem >> 2;
    f32x4* gout = reinterpret_cast<f32x4*>(out + (size_t)r0 * OUTD);
    const f32x4* lsrc = reinterpret_cast<const f32x4*>(olds);
    for (int g = tid; g < nf4; g += THREADS)
        __builtin_nontemporal_store(lsrc[g], gout + g);
    if (tid < (nelem & 3))
        __builtin_nontemporal_store(olds[nf4 * 4 + tid], out + (size_t)r0 * OUTD + nf4 * 4 + tid);
}

extern "C" void kernel_launch(void* const* d_in, const int* in_sizes, int n_in,
                              void* d_out, int out_size, void* d_ws, size_t ws_size,
                              hipStream_t stream) {
    const float* x = (const float*)d_in[0];
    float* out = (float*)d_out;
    const int nrows = in_sizes[0] / D;           // 4*16*8192 = 524288
    const int blocks = (nrows + TILE_ROWS - 1) / TILE_ROWS;   // 32768
    taylor_fm_kernel<<<blocks, THREADS, 0, stream>>>(x, out, nrows);
}

// Round 13
// 63.406 us; speedup vs baseline: 1.0198x; 1.0198x over previous
//
#include <hip/hip_runtime.h>

#define D 16
#define OUTD 153                 // 1 + 16 + 16 + 120
#define TILE_ROWS 32
#define THREADS 256

typedef float f32x4 __attribute__((ext_vector_type(4)));

// FINAL (revert to R11, best measured: 63.4us = 5.6 TB/s effective, 89% of the
// 6.29 TB/s measured mixed-copy ceiling).
//  - 32-row tile, 256 threads, 19.125 KiB LDS -> 8 blocks/CU, 32 waves/CU (cap)
//  - register-held x, compile-time-unrolled emit (2-way divergence per wave, ~40 slots)
//  - LDS row stride 153 (odd) -> conflict-free banks; one barrier per tile
//  - flat float4 NONTEMPORAL stores (evict-first; output is write-once > LLC size;
//    NT was worth -4.4us vs regular stores by keeping x resident in LLC)
// Measured-worse alternatives: barrier-free shuffle (80.2), wave-private slabs (77.8),
// persistent pipelined grid (76.7), 16-row/128-thr (64.7), 64-row/256-thr (72.3).

template<int LO, int HI>
__device__ __forceinline__ void emit_cols(const float xv[D], float* dst) {
    if (LO <= 0 && 0 < HI) dst[0] = 1.0f;
#pragma unroll
    for (int k = 0; k < D; ++k) {
        const int c1 = 1 + k;                    // x / 16^0.25
        if (c1 >= LO && c1 < HI) dst[c1] = xv[k] * 0.5f;
        const int c2 = 17 + k;                   // x^2 / (4*sqrt(2))
        if (c2 >= LO && c2 < HI) dst[c2] = xv[k] * xv[k] * 0.17677669529663687f;
    }
#pragma unroll
    for (int i = 0; i < D; ++i) {
#pragma unroll
        for (int j = i + 1; j < D; ++j) {        // x_i*x_j / 4
            const int c = 33 + (15 * i - (i * (i - 1)) / 2) + (j - i - 1);
            if (c >= LO && c < HI) dst[c] = xv[i] * xv[j] * 0.25f;
        }
    }
}

__global__ __launch_bounds__(THREADS) void taylor_fm_kernel(const float* __restrict__ x,
                                                            float* __restrict__ out,
                                                            int nrows) {
    __shared__ float olds[TILE_ROWS * OUTD];     // 19.125 KiB
    const int tid = threadIdx.x;
    const int r   = tid & 31;                    // row within tile (8 threads per row)
    const int r8  = tid >> 5;                    // col-range id
    const int r0  = blockIdx.x * TILE_ROWS;
    const int row = r0 + r;

    if (row < nrows) {
        const float4* xrow = reinterpret_cast<const float4*>(x + (size_t)row * D);
        float xv[D];
#pragma unroll
        for (int m = 0; m < 4; ++m) {
            float4 v = xrow[m];
            xv[4 * m + 0] = v.x; xv[4 * m + 1] = v.y;
            xv[4 * m + 2] = v.z; xv[4 * m + 3] = v.w;
        }
        float* dst = olds + r * OUTD;            // banks (25r+c)%32: conflict-free
        switch (r8) {
            case 0: emit_cols<0,   20 >(xv, dst); break;
            case 1: emit_cols<20,  39 >(xv, dst); break;
            case 2: emit_cols<39,  58 >(xv, dst); break;
            case 3: emit_cols<58,  77 >(xv, dst); break;
            case 4: emit_cols<77,  96 >(xv, dst); break;
            case 5: emit_cols<96,  115>(xv, dst); break;
            case 6: emit_cols<115, 134>(xv, dst); break;
            case 7: emit_cols<134, 153>(xv, dst); break;
        }
    }
    __syncthreads();

    // Flat, fully coalesced float4 NT stores. Chunk = 19584B, nelem mult of 4.
    const int nrow_blk = min(TILE_ROWS, nrows - r0);
    const int nelem = nrow_blk * OUTD;
    const int nf4 = nelem >> 2;
    f32x4* gout = reinterpret_cast<f32x4*>(out + (size_t)r0 * OUTD);
    const f32x4* lsrc = reinterpret_cast<const f32x4*>(olds);
    for (int g = tid; g < nf4; g += THREADS)
        __builtin_nontemporal_store(lsrc[g], gout + g);
    if (tid < (nelem & 3))
        __builtin_nontemporal_store(olds[nf4 * 4 + tid], out + (size_t)r0 * OUTD + nf4 * 4 + tid);
}

extern "C" void kernel_launch(void* const* d_in, const int* in_sizes, int n_in,
                              void* d_out, int out_size, void* d_ws, size_t ws_size,
                              hipStream_t stream) {
    const float* x = (const float*)d_in[0];
    float* out = (float*)d_out;
    const int nrows = in_sizes[0] / D;           // 4*16*8192 = 524288
    const int blocks = (nrows + TILE_ROWS - 1) / TILE_ROWS;   // 16384
    taylor_fm_kernel<<<blocks, THREADS, 0, stream>>>(x, out, nrows);
}